// Round 5
// baseline (467.285 us; speedup 1.0000x reference)
//
#include <hip/hip_runtime.h>

// RGCN layer, MI355X. Round 5:
//   ws: A[N][512] bf16 (C0|C1), Bt[256][768] bf16, cnt[N], edgebuf[N][32]
//   K1 prep:  fused { build_bt (blocks 0..767), build_edges (768..3892) }
//   K2 agg:   2 dsts per wave, gathers fp32 x directly (2xfloat4/lane),
//             ballot degrees, writes C0|C1 bf16
//   K3 gemm:  128x256 tile; K=768 in 6 stages of 128; B in 64KB fragment-
//             ordered LDS; A-frags: k<512 direct bf16 loads from C panel,
//             k>=512 direct fp32 x loads packed to bf16 in-reg (no conv pass);
//             fused bias+LayerNorm+ReLU

#define NN 100000
#define NR 4
#define NE 200000
#define KDIM 768
#define CAP 32
#define BM 128

typedef __attribute__((ext_vector_type(8))) short short8;
typedef __attribute__((ext_vector_type(16))) float floatx16;

__device__ __forceinline__ unsigned short f2bf(float f) {
  unsigned u = __float_as_uint(f);
  u += 0x7FFFu + ((u >> 16) & 1u);
  return (unsigned short)(u >> 16);
}

// pack 8 fp32 -> 8 bf16 (round-half-up: +0x8000 then take hi16 via v_perm)
__device__ __forceinline__ short8 packbf(float4 a, float4 b) {
  union { unsigned u[4]; short8 s; } r;
  r.u[0] = __builtin_amdgcn_perm(__float_as_uint(a.y) + 0x8000u,
                                 __float_as_uint(a.x) + 0x8000u, 0x07060302u);
  r.u[1] = __builtin_amdgcn_perm(__float_as_uint(a.w) + 0x8000u,
                                 __float_as_uint(a.z) + 0x8000u, 0x07060302u);
  r.u[2] = __builtin_amdgcn_perm(__float_as_uint(b.y) + 0x8000u,
                                 __float_as_uint(b.x) + 0x8000u, 0x07060302u);
  r.u[3] = __builtin_amdgcn_perm(__float_as_uint(b.w) + 0x8000u,
                                 __float_as_uint(b.z) + 0x8000u, 0x07060302u);
  return r.s;
}

__device__ __forceinline__ void gload16(const unsigned short* g, unsigned short* l) {
  __builtin_amdgcn_global_load_lds(
      (const __attribute__((address_space(1))) unsigned int*)g,
      (__attribute__((address_space(3))) unsigned int*)l, 16, 0, 0);
}

// ---------------- K1: fused prep (bt + edge bucketing) ----------------
__global__ void prep(const float* __restrict__ bases, const float* __restrict__ loop_w,
                     const int* __restrict__ src, const int* __restrict__ dst,
                     unsigned short* __restrict__ Bt, int* __restrict__ cnt,
                     int* __restrict__ edgebuf) {
  const int b = blockIdx.x;
  const int tid = threadIdx.x;
  if (b < 768) {
    // build_bt: Bt[n][k] = {bases0, bases1, loop_w}^T in bf16
    int i = b * 256 + tid;  // 768*256 exact
    int n = i & 255;
    int k = i >> 8;
    float v;
    if (k < 256)      v = bases[k * 256 + n];
    else if (k < 512) v = bases[65536 + (k - 256) * 256 + n];
    else              v = loop_w[(k - 512) * 256 + n];
    Bt[(size_t)n * KDIM + k] = f2bf(v);
  } else {
    // build_edges: bucket by dst, one atomic per edge
    int i = (b - 768) * 256 + tid;  // 3125*256 = 800000 exact
    int r = i / NE;
    int s = src[i];
    int dd = dst[i];
    int pos = atomicAdd(&cnt[dd], 1);
    if (pos < CAP) edgebuf[dd * CAP + pos] = s | (r << 20);  // src<2^17, rel bits 20-21
  }
}

// ---------------- K2: aggregation, 2 dsts per wave, fp32 x gathers ----------------
__global__ void agg_edges(const int* __restrict__ edgebuf, const int* __restrict__ cnt,
                          const float* __restrict__ w_comp, const float* __restrict__ x,
                          unsigned short* __restrict__ A) {
  const int tid = threadIdx.x;
  const int lane = tid & 63;
  const int wave = tid >> 6;
  const int half = lane >> 5;
  const int l31 = lane & 31;
  const int d = blockIdx.x * 8 + wave * 2 + half;  // 12500*8 = 100000 exact

  int cc = cnt[d]; cc = cc < CAP ? cc : CAP;
  int ev = 0;
  if (l31 < cc) ev = edgebuf[d * CAP + l31];
  const int rl = ev >> 20;

  unsigned long long b0 = __ballot((l31 < cc) && rl == 0);
  unsigned long long b1 = __ballot((l31 < cc) && rl == 1);
  unsigned long long b2 = __ballot((l31 < cc) && rl == 2);
  unsigned long long b3 = __ballot((l31 < cc) && rl == 3);
  const int sh = half << 5;
  float i0 = 1.0f / fmaxf((float)__popc((unsigned)(b0 >> sh)), 1.0f);
  float i1 = 1.0f / fmaxf((float)__popc((unsigned)(b1 >> sh)), 1.0f);
  float i2 = 1.0f / fmaxf((float)__popc((unsigned)(b2 >> sh)), 1.0f);
  float i3 = 1.0f / fmaxf((float)__popc((unsigned)(b3 >> sh)), 1.0f);
  float s00 = w_comp[0] * i0, s10 = w_comp[1] * i0;
  float s01 = w_comp[2] * i1, s11 = w_comp[3] * i1;
  float s02 = w_comp[4] * i2, s12 = w_comp[5] * i2;
  float s03 = w_comp[6] * i3, s13 = w_comp[7] * i3;

  float a0[8] = {0.f, 0.f, 0.f, 0.f, 0.f, 0.f, 0.f, 0.f};
  float a1[8] = {0.f, 0.f, 0.f, 0.f, 0.f, 0.f, 0.f, 0.f};
  const float* Xp = x + l31 * 8;  // this lane's 8 fp32 cols
  const int selbase = lane & 32;

#define EDGE_W(v, w0, w1)                                            \
  int r_##w0 = (v) >> 20;                                            \
  float w0 = r_##w0 < 2 ? (r_##w0 == 0 ? s00 : s01)                  \
                        : (r_##w0 == 2 ? s02 : s03);                 \
  float w1 = r_##w0 < 2 ? (r_##w0 == 0 ? s10 : s11)                  \
                        : (r_##w0 == 2 ? s12 : s13);

#define ACC8(lo, hi, w0, w1)                                         \
  {                                                                  \
    a0[0] += (w0) * (lo).x; a0[1] += (w0) * (lo).y;                  \
    a0[2] += (w0) * (lo).z; a0[3] += (w0) * (lo).w;                  \
    a0[4] += (w0) * (hi).x; a0[5] += (w0) * (hi).y;                  \
    a0[6] += (w0) * (hi).z; a0[7] += (w0) * (hi).w;                  \
    a1[0] += (w1) * (lo).x; a1[1] += (w1) * (lo).y;                  \
    a1[2] += (w1) * (lo).z; a1[3] += (w1) * (lo).w;                  \
    a1[4] += (w1) * (hi).x; a1[5] += (w1) * (hi).y;                  \
    a1[6] += (w1) * (hi).z; a1[7] += (w1) * (hi).w;                  \
  }

  int i = 0;
  for (; i + 4 <= cc; i += 4) {
    int v0 = __shfl(ev, selbase + i);
    int v1 = __shfl(ev, selbase + i + 1);
    int v2 = __shfl(ev, selbase + i + 2);
    int v3 = __shfl(ev, selbase + i + 3);
    const float* p0 = Xp + (size_t)(v0 & 0xFFFFF) * 256;
    const float* p1 = Xp + (size_t)(v1 & 0xFFFFF) * 256;
    const float* p2 = Xp + (size_t)(v2 & 0xFFFFF) * 256;
    const float* p3 = Xp + (size_t)(v3 & 0xFFFFF) * 256;
    const float4 g0l = *(const float4*)p0, g0h = *(const float4*)(p0 + 4);
    const float4 g1l = *(const float4*)p1, g1h = *(const float4*)(p1 + 4);
    const float4 g2l = *(const float4*)p2, g2h = *(const float4*)(p2 + 4);
    const float4 g3l = *(const float4*)p3, g3h = *(const float4*)(p3 + 4);
    { EDGE_W(v0, w0a, w1a) ACC8(g0l, g0h, w0a, w1a) }
    { EDGE_W(v1, w0b, w1b) ACC8(g1l, g1h, w0b, w1b) }
    { EDGE_W(v2, w0c, w1c) ACC8(g2l, g2h, w0c, w1c) }
    { EDGE_W(v3, w0d, w1d) ACC8(g3l, g3h, w0d, w1d) }
  }
  for (; i < cc; ++i) {
    int v = __shfl(ev, selbase + i);
    const float* p = Xp + (size_t)(v & 0xFFFFF) * 256;
    const float4 gl = *(const float4*)p, gh = *(const float4*)(p + 4);
    EDGE_W(v, w0, w1)
    ACC8(gl, gh, w0, w1)
  }

  uint4 o0, o1;
  o0.x = (unsigned)f2bf(a0[0]) | ((unsigned)f2bf(a0[1]) << 16);
  o0.y = (unsigned)f2bf(a0[2]) | ((unsigned)f2bf(a0[3]) << 16);
  o0.z = (unsigned)f2bf(a0[4]) | ((unsigned)f2bf(a0[5]) << 16);
  o0.w = (unsigned)f2bf(a0[6]) | ((unsigned)f2bf(a0[7]) << 16);
  o1.x = (unsigned)f2bf(a1[0]) | ((unsigned)f2bf(a1[1]) << 16);
  o1.y = (unsigned)f2bf(a1[2]) | ((unsigned)f2bf(a1[3]) << 16);
  o1.z = (unsigned)f2bf(a1[4]) | ((unsigned)f2bf(a1[5]) << 16);
  o1.w = (unsigned)f2bf(a1[6]) | ((unsigned)f2bf(a1[7]) << 16);
  *(uint4*)(A + (size_t)d * 512 + l31 * 8) = o0;
  *(uint4*)(A + (size_t)d * 512 + 256 + l31 * 8) = o1;
}

// ---------------- K3: GEMM + bias + LN + ReLU ----------------
// K=768 in 6 stages of 128. Stages 0..3: A-frags = direct bf16 16B loads from
// C panel (dbuf). Stages 4..5: A-frags = 2xfloat4 from x, packed to bf16.
// B: fragment-ordered 64KB LDS, all ds_read_b128 lane-linear (conflict-free).
__launch_bounds__(256, 2)
__global__ void gemm_ln(const unsigned short* __restrict__ A, const float* __restrict__ x,
                        const unsigned short* __restrict__ Bt,
                        const float* __restrict__ h_bias, const float* __restrict__ gamma,
                        const float* __restrict__ beta, float* __restrict__ out) {
  __shared__ unsigned short Bs[64 * 512];  // (t*8+j)*512 + lane*8, 64 KB
  const int tid = threadIdx.x;
  const int wave = tid >> 6;
  const int lane = tid & 63;
  const int l31 = lane & 31;
  const int half = lane >> 5;
  const int m0 = blockIdx.x * BM;

  floatx16 acc[8];
#pragma unroll
  for (int t = 0; t < 8; ++t)
#pragma unroll
    for (int r = 0; r < 16; ++r) acc[t][r] = 0.0f;

  int arow = m0 + wave * 32 + l31;
  if (arow >= NN) arow = NN - 1;  // tail rows duplicate; outputs guarded
  const unsigned short* gA = A + (size_t)arow * 512 + half * 8;
  const float* gX = x + (size_t)arow * 256 + half * 8;

#define STAGE_B(s)                                                        \
  {                                                                       \
    const int kb = (s) * 128;                                             \
    _Pragma("unroll")                                                     \
    for (int q = 0; q < 16; ++q) {                                        \
      const int t = wave * 2 + (q >> 3);                                  \
      const int j = q & 7;                                                \
      gload16(Bt + (size_t)(t * 32 + l31) * KDIM + kb + j * 16 + half * 8,\
              Bs + (t * 8 + j) * 512 + lane * 8);                         \
    }                                                                     \
  }

  short8 ab[2][8];
  float4 xr[8][2];
#pragma unroll
  for (int j = 0; j < 8; ++j) ab[0][j] = *(const short8*)(gA + j * 16);
  STAGE_B(0)
  __syncthreads();

  // stages 0..3: bf16 C-panel
#pragma unroll
  for (int s = 0; s < 4; ++s) {
    const int cur = s & 1;
    if (s < 3) {
#pragma unroll
      for (int j = 0; j < 8; ++j)
        ab[cur ^ 1][j] = *(const short8*)(gA + (s + 1) * 128 + j * 16);
    } else {
#pragma unroll
      for (int j = 0; j < 8; ++j) {  // prefetch stage-4 fp32 x
        xr[j][0] = *(const float4*)(gX + j * 16);
        xr[j][1] = *(const float4*)(gX + j * 16 + 4);
      }
    }
#pragma unroll
    for (int j = 0; j < 8; ++j) {
      short8 af = ab[cur][j];
#pragma unroll
      for (int t = 0; t < 8; ++t) {
        short8 bfr = *(const short8*)(Bs + (t * 8 + j) * 512 + lane * 8);
        acc[t] = __builtin_amdgcn_mfma_f32_32x32x16_bf16(af, bfr, acc[t], 0, 0, 0);
      }
    }
    __syncthreads();
    STAGE_B(s + 1)
    __syncthreads();
  }

  // stages 4..5: fp32 x packed to bf16
#pragma unroll
  for (int s = 4; s < 6; ++s) {
#pragma unroll
    for (int j = 0; j < 8; ++j) {
      short8 af = packbf(xr[j][0], xr[j][1]);
#pragma unroll
      for (int t = 0; t < 8; ++t) {
        short8 bfr = *(const short8*)(Bs + (t * 8 + j) * 512 + lane * 8);
        acc[t] = __builtin_amdgcn_mfma_f32_32x32x16_bf16(af, bfr, acc[t], 0, 0, 0);
      }
    }
    if (s == 4) {
#pragma unroll
      for (int j = 0; j < 8; ++j) {  // stage-5 fp32 x
        xr[j][0] = *(const float4*)(gX + 128 + j * 16);
        xr[j][1] = *(const float4*)(gX + 128 + j * 16 + 4);
      }
      __syncthreads();
      STAGE_B(5)
      __syncthreads();
    }
  }

  // epilogue: bias, LayerNorm over 256 cols, gamma/beta, ReLU
  float bcol[8], gc[8], bc[8];
#pragma unroll
  for (int t = 0; t < 8; ++t) {
    int col = t * 32 + l31;
    bcol[t] = h_bias[col];
    gc[t] = gamma[col];
    bc[t] = beta[col];
  }
#pragma unroll
  for (int t = 0; t < 8; ++t)
#pragma unroll
    for (int r = 0; r < 16; ++r) acc[t][r] += bcol[t];

  const int m_base = m0 + wave * 32;
#pragma unroll
  for (int r = 0; r < 16; ++r) {
    float s = 0.f, q = 0.f;
#pragma unroll
    for (int t = 0; t < 8; ++t) { float v = acc[t][r]; s += v; q += v * v; }
#pragma unroll
    for (int m = 16; m >= 1; m >>= 1) {
      s += __shfl_xor(s, m);
      q += __shfl_xor(q, m);
    }
    float mean = s * (1.0f / 256.0f);
    float var = q * (1.0f / 256.0f) - mean * mean;
    float rstd = rsqrtf(var + 1e-5f);
    int row = (r & 3) + ((r >> 2) << 3) + (half << 2);  // C/D layout, 32x32
    int grow = m_base + row;
    if (grow < NN) {
#pragma unroll
      for (int t = 0; t < 8; ++t) {
        float v = (acc[t][r] - mean) * rstd * gc[t] + bc[t];
        out[(size_t)grow * 256 + t * 32 + l31] = fmaxf(v, 0.0f);
      }
    }
  }
}

extern "C" void kernel_launch(void* const* d_in, const int* in_sizes, int n_in,
                              void* d_out, int out_size, void* d_ws, size_t ws_size,
                              hipStream_t stream) {
  const float* x      = (const float*)d_in[0];
  const int*   src    = (const int*)d_in[1];
  const int*   dst    = (const int*)d_in[2];
  const float* bases  = (const float*)d_in[3];
  const float* w_comp = (const float*)d_in[4];
  const float* loop_w = (const float*)d_in[5];
  const float* h_bias = (const float*)d_in[6];
  const float* gamma  = (const float*)d_in[7];
  const float* beta   = (const float*)d_in[8];
  float* out = (float*)d_out;

  char* ws = (char*)d_ws;
  unsigned short* A  = (unsigned short*)ws;                // 102,400,000 B
  unsigned short* Bt = (unsigned short*)(ws + 102400000);  //     393,216 B
  int* cnt     = (int*)(ws + 102793216);                   //     400,000 B
  int* edgebuf = (int*)(ws + 103193216);                   //  12,800,000 B
  // total 115,993,216 B

  hipMemsetAsync(cnt, 0, 400000, stream);

  prep<<<3893, 256, 0, stream>>>(bases, loop_w, src, dst, Bt, cnt, edgebuf);
  agg_edges<<<12500, 256, 0, stream>>>(edgebuf, cnt, w_comp, x, A);
  gemm_ln<<<(NN + BM - 1) / BM, 256, 0, stream>>>(A, x, Bt, h_bias, gamma, beta, out);
}

// Round 6
// 432.796 us; speedup vs baseline: 1.0797x; 1.0797x over previous
//
#include <hip/hip_runtime.h>

// RGCN layer, MI355X. Round 6:
//   ws: Cp[N][512] bf16 (C0|C1), Xbf[N][256] bf16, Bfrag[6][8][8][64][8] bf16,
//       cnt[N], edgebuf[N][32]
//   K1 prep:  fused { conv_x -> Xbf (blocks 0..12499), build Bfrag in MFMA
//             fragment order (12500..13267), edge bucketing (13268..16392) }
//   K2 agg:   2 dsts per wave, bf16 uint4/lane gathers from compact Xbf,
//             ballot degrees, writes Cp
//   K3 gemm:  128x256 tile, NO LDS / NO barriers: B-frags broadcast-loaded
//             from pre-swizzled Bfrag (L1/L2-hot), A-frags per-lane direct
//             16B loads; stage-level A dbuf + j-level B dbuf;
//             fused bias+LayerNorm+ReLU

#define NN 100000
#define NR 4
#define NE 200000
#define CAP 32
#define BM 128

typedef __attribute__((ext_vector_type(8))) short short8;
typedef __attribute__((ext_vector_type(16))) float floatx16;

__device__ __forceinline__ unsigned short f2bf(float f) {
  unsigned u = __float_as_uint(f);
  u += 0x7FFFu + ((u >> 16) & 1u);
  return (unsigned short)(u >> 16);
}

// ---------------- K1: fused prep ----------------
__global__ void prep(const float* __restrict__ x, const float* __restrict__ bases,
                     const float* __restrict__ loop_w, const int* __restrict__ src,
                     const int* __restrict__ dst, unsigned short* __restrict__ Xbf,
                     unsigned short* __restrict__ Bfrag, int* __restrict__ cnt,
                     int* __restrict__ edgebuf) {
  const int b = blockIdx.x;
  const int tid = threadIdx.x;
  if (b < 12500) {
    // conv_x: x fp32 -> bf16 compact panel; 8 cols per thread
    int i = b * 256 + tid;  // 3.2M threads exact
    int row = i >> 5;
    int col = (i & 31) << 3;
    const float4 v0 = *(const float4*)(x + (size_t)row * 256 + col);
    const float4 v1 = *(const float4*)(x + (size_t)row * 256 + col + 4);
    uint4 u;
    u.x = (unsigned)f2bf(v0.x) | ((unsigned)f2bf(v0.y) << 16);
    u.y = (unsigned)f2bf(v0.z) | ((unsigned)f2bf(v0.w) << 16);
    u.z = (unsigned)f2bf(v1.x) | ((unsigned)f2bf(v1.y) << 16);
    u.w = (unsigned)f2bf(v1.z) | ((unsigned)f2bf(v1.w) << 16);
    *(uint4*)(Xbf + (size_t)row * 256 + col) = u;
  } else if (b < 13268) {
    // Bfrag: fragment-major B. idx = ((s*8+j)*8+t)*512 + lane*8 + e
    // maps to n = t*32+(lane&31), k = s*128 + j*16 + (lane>>5)*8 + e
    int i = (b - 12500) * 256 + tid;  // 196608 exact
    int e = i & 7;
    int lane = (i >> 3) & 63;
    int f = i >> 9;
    int t = f & 7;
    int j = (f >> 3) & 7;
    int s = f >> 6;
    int n = t * 32 + (lane & 31);
    int k = s * 128 + j * 16 + (lane >> 5) * 8 + e;
    float v;
    if (k < 256)      v = bases[k * 256 + n];
    else if (k < 512) v = bases[65536 + (k - 256) * 256 + n];
    else              v = loop_w[(k - 512) * 256 + n];
    Bfrag[i] = f2bf(v);
  } else {
    // edge bucketing: one atomic per edge
    int i = (b - 13268) * 256 + tid;  // 3125*256 = 800000 exact
    int r = i / NE;
    int s = src[i];
    int dd = dst[i];
    int pos = atomicAdd(&cnt[dd], 1);
    if (pos < CAP) edgebuf[dd * CAP + pos] = s | (r << 20);  // src<2^17, rel bits 20-21
  }
}

// ---------------- K2: aggregation, 2 dsts per wave, bf16 16B/lane gathers ----------------
__global__ void agg_edges(const int* __restrict__ edgebuf, const int* __restrict__ cnt,
                          const float* __restrict__ w_comp,
                          const unsigned short* __restrict__ Xbf,
                          unsigned short* __restrict__ Cp) {
  const int tid = threadIdx.x;
  const int lane = tid & 63;
  const int wave = tid >> 6;
  const int half = lane >> 5;
  const int l31 = lane & 31;
  const int d = blockIdx.x * 8 + wave * 2 + half;  // 12500*8 = 100000 exact

  int cc = cnt[d]; cc = cc < CAP ? cc : CAP;
  int ev = 0;
  if (l31 < cc) ev = edgebuf[d * CAP + l31];
  const int rl = ev >> 20;

  unsigned long long b0 = __ballot((l31 < cc) && rl == 0);
  unsigned long long b1 = __ballot((l31 < cc) && rl == 1);
  unsigned long long b2 = __ballot((l31 < cc) && rl == 2);
  unsigned long long b3 = __ballot((l31 < cc) && rl == 3);
  const int sh = half << 5;
  float i0 = 1.0f / fmaxf((float)__popc((unsigned)(b0 >> sh)), 1.0f);
  float i1 = 1.0f / fmaxf((float)__popc((unsigned)(b1 >> sh)), 1.0f);
  float i2 = 1.0f / fmaxf((float)__popc((unsigned)(b2 >> sh)), 1.0f);
  float i3 = 1.0f / fmaxf((float)__popc((unsigned)(b3 >> sh)), 1.0f);
  float s00 = w_comp[0] * i0, s10 = w_comp[1] * i0;
  float s01 = w_comp[2] * i1, s11 = w_comp[3] * i1;
  float s02 = w_comp[4] * i2, s12 = w_comp[5] * i2;
  float s03 = w_comp[6] * i3, s13 = w_comp[7] * i3;

  float a0[8] = {0.f, 0.f, 0.f, 0.f, 0.f, 0.f, 0.f, 0.f};
  float a1[8] = {0.f, 0.f, 0.f, 0.f, 0.f, 0.f, 0.f, 0.f};
  const unsigned short* Xp = Xbf + l31 * 8;  // this lane's 16B of the row
  const int selbase = lane & 32;

#define EDGE_W(v, w0, w1)                                            \
  int r_##w0 = (v) >> 20;                                            \
  float w0 = r_##w0 < 2 ? (r_##w0 == 0 ? s00 : s01)                  \
                        : (r_##w0 == 2 ? s02 : s03);                 \
  float w1 = r_##w0 < 2 ? (r_##w0 == 0 ? s10 : s11)                  \
                        : (r_##w0 == 2 ? s12 : s13);

#define ACC8(g, w0, w1)                                              \
  {                                                                  \
    float e0 = __uint_as_float((g).x << 16);                         \
    float e1 = __uint_as_float((g).x & 0xFFFF0000u);                 \
    float e2 = __uint_as_float((g).y << 16);                         \
    float e3 = __uint_as_float((g).y & 0xFFFF0000u);                 \
    float e4 = __uint_as_float((g).z << 16);                         \
    float e5 = __uint_as_float((g).z & 0xFFFF0000u);                 \
    float e6 = __uint_as_float((g).w << 16);                         \
    float e7 = __uint_as_float((g).w & 0xFFFF0000u);                 \
    a0[0] += (w0) * e0; a0[1] += (w0) * e1; a0[2] += (w0) * e2;      \
    a0[3] += (w0) * e3; a0[4] += (w0) * e4; a0[5] += (w0) * e5;      \
    a0[6] += (w0) * e6; a0[7] += (w0) * e7;                          \
    a1[0] += (w1) * e0; a1[1] += (w1) * e1; a1[2] += (w1) * e2;      \
    a1[3] += (w1) * e3; a1[4] += (w1) * e4; a1[5] += (w1) * e5;      \
    a1[6] += (w1) * e6; a1[7] += (w1) * e7;                          \
  }

  int i = 0;
  for (; i + 4 <= cc; i += 4) {
    int v0 = __shfl(ev, selbase + i);
    int v1 = __shfl(ev, selbase + i + 1);
    int v2 = __shfl(ev, selbase + i + 2);
    int v3 = __shfl(ev, selbase + i + 3);
    const uint4 g0 = *(const uint4*)(Xp + (size_t)(v0 & 0xFFFFF) * 256);
    const uint4 g1 = *(const uint4*)(Xp + (size_t)(v1 & 0xFFFFF) * 256);
    const uint4 g2 = *(const uint4*)(Xp + (size_t)(v2 & 0xFFFFF) * 256);
    const uint4 g3 = *(const uint4*)(Xp + (size_t)(v3 & 0xFFFFF) * 256);
    { EDGE_W(v0, w0a, w1a) ACC8(g0, w0a, w1a) }
    { EDGE_W(v1, w0b, w1b) ACC8(g1, w0b, w1b) }
    { EDGE_W(v2, w0c, w1c) ACC8(g2, w0c, w1c) }
    { EDGE_W(v3, w0d, w1d) ACC8(g3, w0d, w1d) }
  }
  for (; i < cc; ++i) {
    int v = __shfl(ev, selbase + i);
    const uint4 g = *(const uint4*)(Xp + (size_t)(v & 0xFFFFF) * 256);
    EDGE_W(v, w0, w1)
    ACC8(g, w0, w1)
  }

  uint4 o0, o1;
  o0.x = (unsigned)f2bf(a0[0]) | ((unsigned)f2bf(a0[1]) << 16);
  o0.y = (unsigned)f2bf(a0[2]) | ((unsigned)f2bf(a0[3]) << 16);
  o0.z = (unsigned)f2bf(a0[4]) | ((unsigned)f2bf(a0[5]) << 16);
  o0.w = (unsigned)f2bf(a0[6]) | ((unsigned)f2bf(a0[7]) << 16);
  o1.x = (unsigned)f2bf(a1[0]) | ((unsigned)f2bf(a1[1]) << 16);
  o1.y = (unsigned)f2bf(a1[2]) | ((unsigned)f2bf(a1[3]) << 16);
  o1.z = (unsigned)f2bf(a1[4]) | ((unsigned)f2bf(a1[5]) << 16);
  o1.w = (unsigned)f2bf(a1[6]) | ((unsigned)f2bf(a1[7]) << 16);
  *(uint4*)(Cp + (size_t)d * 512 + l31 * 8) = o0;
  *(uint4*)(Cp + (size_t)d * 512 + 256 + l31 * 8) = o1;
}

// ---------------- K3: GEMM + bias + LN + ReLU (no LDS, no barriers) ----------------
__launch_bounds__(256, 2)
__global__ void gemm_ln(const unsigned short* __restrict__ Cp,
                        const unsigned short* __restrict__ Xbf,
                        const unsigned short* __restrict__ Bfrag,
                        const float* __restrict__ h_bias, const float* __restrict__ gamma,
                        const float* __restrict__ beta, float* __restrict__ out) {
  const int tid = threadIdx.x;
  const int wave = tid >> 6;
  const int lane = tid & 63;
  const int l31 = lane & 31;
  const int half = lane >> 5;
  const int m0 = blockIdx.x * BM;

  floatx16 acc[8];
#pragma unroll
  for (int t = 0; t < 8; ++t)
#pragma unroll
    for (int r = 0; r < 16; ++r) acc[t][r] = 0.0f;

  int arow = m0 + wave * 32 + l31;
  if (arow >= NN) arow = NN - 1;  // tail rows duplicate; outputs guarded
  const unsigned short* gC = Cp + (size_t)arow * 512 + half * 8;
  const unsigned short* gX = Xbf + (size_t)arow * 256 + half * 8;
  const unsigned short* gB = Bfrag + lane * 8;

  short8 Af[2][8];
  short8 Bf[2][8];

  // preload stage-0 A frags and (s=0,j=0) B frags
#pragma unroll
  for (int j = 0; j < 8; ++j) Af[0][j] = *(const short8*)(gC + j * 16);
#pragma unroll
  for (int t = 0; t < 8; ++t) Bf[0][t] = *(const short8*)(gB + t * 512);

#pragma unroll
  for (int s = 0; s < 6; ++s) {
    // prefetch next stage's A frags into the other buffer
    if (s < 5) {
      const unsigned short* ap =
          (s + 1 < 4) ? gC + (s + 1) * 128 : gX + (s + 1 - 4) * 128;
#pragma unroll
      for (int j = 0; j < 8; ++j)
        Af[(s + 1) & 1][j] = *(const short8*)(ap + j * 16);
    }
#pragma unroll
    for (int j = 0; j < 8; ++j) {
      const int cur = j & 1;
      // prefetch next j's B frags
      if (!(s == 5 && j == 7)) {
        const int ns = (j == 7) ? s + 1 : s;
        const int nj = (j + 1) & 7;
        const unsigned short* bp = gB + (size_t)(ns * 8 + nj) * 8 * 512;
#pragma unroll
        for (int t = 0; t < 8; ++t)
          Bf[cur ^ 1][t] = *(const short8*)(bp + t * 512);
      }
      short8 af = Af[s & 1][j];
#pragma unroll
      for (int t = 0; t < 8; ++t)
        acc[t] = __builtin_amdgcn_mfma_f32_32x32x16_bf16(af, Bf[cur][t], acc[t], 0, 0, 0);
    }
  }

  // epilogue: bias, LayerNorm over 256 cols, gamma/beta, ReLU
  float bcol[8], gc[8], bc[8];
#pragma unroll
  for (int t = 0; t < 8; ++t) {
    int col = t * 32 + l31;
    bcol[t] = h_bias[col];
    gc[t] = gamma[col];
    bc[t] = beta[col];
  }
#pragma unroll
  for (int t = 0; t < 8; ++t)
#pragma unroll
    for (int r = 0; r < 16; ++r) acc[t][r] += bcol[t];

  const int m_base = m0 + wave * 32;
#pragma unroll
  for (int r = 0; r < 16; ++r) {
    float s = 0.f, q = 0.f;
#pragma unroll
    for (int t = 0; t < 8; ++t) { float v = acc[t][r]; s += v; q += v * v; }
#pragma unroll
    for (int m = 16; m >= 1; m >>= 1) {
      s += __shfl_xor(s, m);
      q += __shfl_xor(q, m);
    }
    float mean = s * (1.0f / 256.0f);
    float var = q * (1.0f / 256.0f) - mean * mean;
    float rstd = rsqrtf(var + 1e-5f);
    int row = (r & 3) + ((r >> 2) << 3) + (half << 2);  // C/D layout, 32x32
    int grow = m_base + row;
    if (grow < NN) {
#pragma unroll
      for (int t = 0; t < 8; ++t) {
        float v = (acc[t][r] - mean) * rstd * gc[t] + bc[t];
        out[(size_t)grow * 256 + t * 32 + l31] = fmaxf(v, 0.0f);
      }
    }
  }
}

extern "C" void kernel_launch(void* const* d_in, const int* in_sizes, int n_in,
                              void* d_out, int out_size, void* d_ws, size_t ws_size,
                              hipStream_t stream) {
  const float* x      = (const float*)d_in[0];
  const int*   src    = (const int*)d_in[1];
  const int*   dst    = (const int*)d_in[2];
  const float* bases  = (const float*)d_in[3];
  const float* w_comp = (const float*)d_in[4];
  const float* loop_w = (const float*)d_in[5];
  const float* h_bias = (const float*)d_in[6];
  const float* gamma  = (const float*)d_in[7];
  const float* beta   = (const float*)d_in[8];
  float* out = (float*)d_out;

  char* ws = (char*)d_ws;
  unsigned short* Cp    = (unsigned short*)ws;                // 102,400,000 B
  unsigned short* Xbf   = (unsigned short*)(ws + 102400000);  //  51,200,000 B
  unsigned short* Bfrag = (unsigned short*)(ws + 153600000);  //     393,216 B
  int* cnt     = (int*)(ws + 153993216);                      //     400,000 B
  int* edgebuf = (int*)(ws + 154393216);                      //  12,800,000 B
  // total 167,193,216 B

  hipMemsetAsync(cnt, 0, 400000, stream);

  prep<<<16393, 256, 0, stream>>>(x, bases, loop_w, src, dst, Xbf, Bfrag, cnt, edgebuf);
  agg_edges<<<12500, 256, 0, stream>>>(edgebuf, cnt, w_comp, Xbf, Cp);
  gemm_ln<<<(NN + BM - 1) / BM, 256, 0, stream>>>(Cp, Xbf, Bfrag, h_bias, gamma, beta, out);
}

// Round 7
// 382.499 us; speedup vs baseline: 1.2217x; 1.1315x over previous
//
#include <hip/hip_runtime.h>

// RGCN layer, MI355X. Round 7:
//   ws: Cp[N][512] bf16 (C0|C1), Xbf[N][256] bf16, Bfrag[6][8][8][64][8] bf16,
//       cnt[N], edgebuf[N][32]
//   K1 prep:  fused { conv_x -> Xbf, build Bfrag (MFMA fragment order),
//                     edge bucketing }
//   K2 agg:   2 dsts per wave, bf16 uint4/lane gathers from compact Xbf
//   K3 gemm:  128x256 tile, BK=32, A+B double-buffered in LDS via
//             global_load_lds (48KB, 2 blocks/CU); stage s+1 issued BEFORE
//             stage-s compute so the barrier drain is pre-covered;
//             fragment-ordered LDS -> all ds_read_b128 lane-linear;
//             fused bias+LayerNorm+ReLU

#define NN 100000
#define NR 4
#define NE 200000
#define CAP 32
#define BM 128

typedef __attribute__((ext_vector_type(8))) short short8;
typedef __attribute__((ext_vector_type(16))) float floatx16;

__device__ __forceinline__ unsigned short f2bf(float f) {
  unsigned u = __float_as_uint(f);
  u += 0x7FFFu + ((u >> 16) & 1u);
  return (unsigned short)(u >> 16);
}

__device__ __forceinline__ void gload16(const unsigned short* g, unsigned short* l) {
  __builtin_amdgcn_global_load_lds(
      (const __attribute__((address_space(1))) unsigned int*)g,
      (__attribute__((address_space(3))) unsigned int*)l, 16, 0, 0);
}

// ---------------- K1: fused prep ----------------
__global__ void prep(const float* __restrict__ x, const float* __restrict__ bases,
                     const float* __restrict__ loop_w, const int* __restrict__ src,
                     const int* __restrict__ dst, unsigned short* __restrict__ Xbf,
                     unsigned short* __restrict__ Bfrag, int* __restrict__ cnt,
                     int* __restrict__ edgebuf) {
  const int b = blockIdx.x;
  const int tid = threadIdx.x;
  if (b < 12500) {
    // conv_x: x fp32 -> bf16 compact panel; 8 cols per thread
    int i = b * 256 + tid;  // 3.2M threads exact
    int row = i >> 5;
    int col = (i & 31) << 3;
    const float4 v0 = *(const float4*)(x + (size_t)row * 256 + col);
    const float4 v1 = *(const float4*)(x + (size_t)row * 256 + col + 4);
    uint4 u;
    u.x = (unsigned)f2bf(v0.x) | ((unsigned)f2bf(v0.y) << 16);
    u.y = (unsigned)f2bf(v0.z) | ((unsigned)f2bf(v0.w) << 16);
    u.z = (unsigned)f2bf(v1.x) | ((unsigned)f2bf(v1.y) << 16);
    u.w = (unsigned)f2bf(v1.z) | ((unsigned)f2bf(v1.w) << 16);
    *(uint4*)(Xbf + (size_t)row * 256 + col) = u;
  } else if (b < 13268) {
    // Bfrag: fragment-major B. idx = ((s*8+j)*8+t)*512 + lane*8 + e
    // maps to n = t*32+(lane&31), k = s*128 + j*16 + (lane>>5)*8 + e
    int i = (b - 12500) * 256 + tid;  // 196608 exact
    int e = i & 7;
    int lane = (i >> 3) & 63;
    int f = i >> 9;
    int t = f & 7;
    int j = (f >> 3) & 7;
    int s = f >> 6;
    int n = t * 32 + (lane & 31);
    int k = s * 128 + j * 16 + (lane >> 5) * 8 + e;
    float v;
    if (k < 256)      v = bases[k * 256 + n];
    else if (k < 512) v = bases[65536 + (k - 256) * 256 + n];
    else              v = loop_w[(k - 512) * 256 + n];
    Bfrag[i] = f2bf(v);
  } else {
    // edge bucketing: one atomic per edge
    int i = (b - 13268) * 256 + tid;  // 3125*256 = 800000 exact
    int r = i / NE;
    int s = src[i];
    int dd = dst[i];
    int pos = atomicAdd(&cnt[dd], 1);
    if (pos < CAP) edgebuf[dd * CAP + pos] = s | (r << 20);  // src<2^17, rel bits 20-21
  }
}

// ---------------- K2: aggregation, 2 dsts per wave, bf16 16B/lane gathers ----------------
__global__ void agg_edges(const int* __restrict__ edgebuf, const int* __restrict__ cnt,
                          const float* __restrict__ w_comp,
                          const unsigned short* __restrict__ Xbf,
                          unsigned short* __restrict__ Cp) {
  const int tid = threadIdx.x;
  const int lane = tid & 63;
  const int wave = tid >> 6;
  const int half = lane >> 5;
  const int l31 = lane & 31;
  const int d = blockIdx.x * 8 + wave * 2 + half;  // 12500*8 = 100000 exact

  int cc = cnt[d]; cc = cc < CAP ? cc : CAP;
  int ev = 0;
  if (l31 < cc) ev = edgebuf[d * CAP + l31];
  const int rl = ev >> 20;

  unsigned long long b0 = __ballot((l31 < cc) && rl == 0);
  unsigned long long b1 = __ballot((l31 < cc) && rl == 1);
  unsigned long long b2 = __ballot((l31 < cc) && rl == 2);
  unsigned long long b3 = __ballot((l31 < cc) && rl == 3);
  const int sh = half << 5;
  float i0 = 1.0f / fmaxf((float)__popc((unsigned)(b0 >> sh)), 1.0f);
  float i1 = 1.0f / fmaxf((float)__popc((unsigned)(b1 >> sh)), 1.0f);
  float i2 = 1.0f / fmaxf((float)__popc((unsigned)(b2 >> sh)), 1.0f);
  float i3 = 1.0f / fmaxf((float)__popc((unsigned)(b3 >> sh)), 1.0f);
  float s00 = w_comp[0] * i0, s10 = w_comp[1] * i0;
  float s01 = w_comp[2] * i1, s11 = w_comp[3] * i1;
  float s02 = w_comp[4] * i2, s12 = w_comp[5] * i2;
  float s03 = w_comp[6] * i3, s13 = w_comp[7] * i3;

  float a0[8] = {0.f, 0.f, 0.f, 0.f, 0.f, 0.f, 0.f, 0.f};
  float a1[8] = {0.f, 0.f, 0.f, 0.f, 0.f, 0.f, 0.f, 0.f};
  const unsigned short* Xp = Xbf + l31 * 8;
  const int selbase = lane & 32;

#define EDGE_W(v, w0, w1)                                            \
  int r_##w0 = (v) >> 20;                                            \
  float w0 = r_##w0 < 2 ? (r_##w0 == 0 ? s00 : s01)                  \
                        : (r_##w0 == 2 ? s02 : s03);                 \
  float w1 = r_##w0 < 2 ? (r_##w0 == 0 ? s10 : s11)                  \
                        : (r_##w0 == 2 ? s12 : s13);

#define ACC8(g, w0, w1)                                              \
  {                                                                  \
    float e0 = __uint_as_float((g).x << 16);                         \
    float e1 = __uint_as_float((g).x & 0xFFFF0000u);                 \
    float e2 = __uint_as_float((g).y << 16);                         \
    float e3 = __uint_as_float((g).y & 0xFFFF0000u);                 \
    float e4 = __uint_as_float((g).z << 16);                         \
    float e5 = __uint_as_float((g).z & 0xFFFF0000u);                 \
    float e6 = __uint_as_float((g).w << 16);                         \
    float e7 = __uint_as_float((g).w & 0xFFFF0000u);                 \
    a0[0] += (w0) * e0; a0[1] += (w0) * e1; a0[2] += (w0) * e2;      \
    a0[3] += (w0) * e3; a0[4] += (w0) * e4; a0[5] += (w0) * e5;      \
    a0[6] += (w0) * e6; a0[7] += (w0) * e7;                          \
    a1[0] += (w1) * e0; a1[1] += (w1) * e1; a1[2] += (w1) * e2;      \
    a1[3] += (w1) * e3; a1[4] += (w1) * e4; a1[5] += (w1) * e5;      \
    a1[6] += (w1) * e6; a1[7] += (w1) * e7;                          \
  }

  int i = 0;
  for (; i + 4 <= cc; i += 4) {
    int v0 = __shfl(ev, selbase + i);
    int v1 = __shfl(ev, selbase + i + 1);
    int v2 = __shfl(ev, selbase + i + 2);
    int v3 = __shfl(ev, selbase + i + 3);
    const uint4 g0 = *(const uint4*)(Xp + (size_t)(v0 & 0xFFFFF) * 256);
    const uint4 g1 = *(const uint4*)(Xp + (size_t)(v1 & 0xFFFFF) * 256);
    const uint4 g2 = *(const uint4*)(Xp + (size_t)(v2 & 0xFFFFF) * 256);
    const uint4 g3 = *(const uint4*)(Xp + (size_t)(v3 & 0xFFFFF) * 256);
    { EDGE_W(v0, w0a, w1a) ACC8(g0, w0a, w1a) }
    { EDGE_W(v1, w0b, w1b) ACC8(g1, w0b, w1b) }
    { EDGE_W(v2, w0c, w1c) ACC8(g2, w0c, w1c) }
    { EDGE_W(v3, w0d, w1d) ACC8(g3, w0d, w1d) }
  }
  for (; i < cc; ++i) {
    int v = __shfl(ev, selbase + i);
    const uint4 g = *(const uint4*)(Xp + (size_t)(v & 0xFFFFF) * 256);
    EDGE_W(v, w0, w1)
    ACC8(g, w0, w1)
  }

  uint4 o0, o1;
  o0.x = (unsigned)f2bf(a0[0]) | ((unsigned)f2bf(a0[1]) << 16);
  o0.y = (unsigned)f2bf(a0[2]) | ((unsigned)f2bf(a0[3]) << 16);
  o0.z = (unsigned)f2bf(a0[4]) | ((unsigned)f2bf(a0[5]) << 16);
  o0.w = (unsigned)f2bf(a0[6]) | ((unsigned)f2bf(a0[7]) << 16);
  o1.x = (unsigned)f2bf(a1[0]) | ((unsigned)f2bf(a1[1]) << 16);
  o1.y = (unsigned)f2bf(a1[2]) | ((unsigned)f2bf(a1[3]) << 16);
  o1.z = (unsigned)f2bf(a1[4]) | ((unsigned)f2bf(a1[5]) << 16);
  o1.w = (unsigned)f2bf(a1[6]) | ((unsigned)f2bf(a1[7]) << 16);
  *(uint4*)(Cp + (size_t)d * 512 + l31 * 8) = o0;
  *(uint4*)(Cp + (size_t)d * 512 + 256 + l31 * 8) = o1;
}

// ---------------- K3: GEMM + bias + LN + ReLU (vmcnt-pipelined LDS dbuf) ----------------
// 24 stages of BK=32. Per stage: A 8KB (2 gload16/thread, per-lane gathered
// fragments), B 16KB (4 gload16/thread, contiguous Bfrag slice). Prefetch of
// stage s+1 is issued BEFORE stage-s MFMAs; __syncthreads after compute.
__launch_bounds__(256, 2)
__global__ void gemm_ln(const unsigned short* __restrict__ Cp,
                        const unsigned short* __restrict__ Xbf,
                        const unsigned short* __restrict__ Bfrag,
                        const float* __restrict__ h_bias, const float* __restrict__ gamma,
                        const float* __restrict__ beta, float* __restrict__ out) {
  __shared__ unsigned short Ab[2][128 * 32];  // [buf][(w*2+j)*64 + lane][8]  16 KB
  __shared__ unsigned short Bb[2][256 * 32];  // [buf][(j*8+t)*512 + lane*8]  32 KB
  const int tid = threadIdx.x;
  const int wave = tid >> 6;
  const int lane = tid & 63;
  const int l31 = lane & 31;
  const int half = lane >> 5;
  const int m0 = blockIdx.x * BM;

  floatx16 acc[8];
#pragma unroll
  for (int t = 0; t < 8; ++t)
#pragma unroll
    for (int r = 0; r < 16; ++r) acc[t][r] = 0.0f;

  // A staging: instruction (wave, q) covers fragment block (w=wave, j=q):
  // lane sl -> row m0+32*wave+(sl&31), k = 32*s + q*16 + (sl>>5)*8
  int arow = m0 + 32 * wave + l31;
  if (arow >= NN) arow = NN - 1;  // dup tail rows; outputs guarded
  const unsigned short* pC0 = Cp + (size_t)arow * 512 + half * 8;        // q=0
  const unsigned short* pC1 = pC0 + 16;                                   // q=1
  const unsigned short* pX0 = Xbf + (size_t)arow * 256 + half * 8;
  const unsigned short* pX1 = pX0 + 16;
  // B staging: contiguous copy, thread tid moves 4 x 16B
  const unsigned short* pB = Bfrag + tid * 8;

#define STAGE(s, buf)                                                     \
  {                                                                       \
    const int ks = (s) * 32;                                              \
    const unsigned short* a0 = ((s) < 16) ? pC0 + ks : pX0 + ks - 512;    \
    const unsigned short* a1 = ((s) < 16) ? pC1 + ks : pX1 + ks - 512;    \
    gload16(a0, &Ab[buf][(wave * 2 + 0) * 64 * 8] + lane * 8);            \
    gload16(a1, &Ab[buf][(wave * 2 + 1) * 64 * 8] + lane * 8);            \
    const unsigned short* bsrc = pB + (size_t)(s) * 8192;                 \
    gload16(bsrc,        &Bb[buf][0]    + tid * 8);                       \
    gload16(bsrc + 2048, &Bb[buf][2048] + tid * 8);                       \
    gload16(bsrc + 4096, &Bb[buf][4096] + tid * 8);                       \
    gload16(bsrc + 6144, &Bb[buf][6144] + tid * 8);                       \
  }

  STAGE(0, 0)
  __syncthreads();

  for (int s = 0; s < 24; ++s) {
    const int cur = s & 1;
    if (s < 23) STAGE(s + 1, cur ^ 1)
#pragma unroll
    for (int j = 0; j < 2; ++j) {
      short8 af = *(const short8*)(&Ab[cur][(wave * 2 + j) * 512] + lane * 8);
#pragma unroll
      for (int t = 0; t < 8; ++t) {
        short8 bfr = *(const short8*)(&Bb[cur][(j * 8 + t) * 512] + lane * 8);
        acc[t] = __builtin_amdgcn_mfma_f32_32x32x16_bf16(af, bfr, acc[t], 0, 0, 0);
      }
    }
    __syncthreads();
  }

  // epilogue: bias, LayerNorm over 256 cols, gamma/beta, ReLU
  float bcol[8], gc[8], bc[8];
#pragma unroll
  for (int t = 0; t < 8; ++t) {
    int col = t * 32 + l31;
    bcol[t] = h_bias[col];
    gc[t] = gamma[col];
    bc[t] = beta[col];
  }
#pragma unroll
  for (int t = 0; t < 8; ++t)
#pragma unroll
    for (int r = 0; r < 16; ++r) acc[t][r] += bcol[t];

  const int m_base = m0 + wave * 32;
#pragma unroll
  for (int r = 0; r < 16; ++r) {
    float s = 0.f, q = 0.f;
#pragma unroll
    for (int t = 0; t < 8; ++t) { float v = acc[t][r]; s += v; q += v * v; }
#pragma unroll
    for (int m = 16; m >= 1; m >>= 1) {
      s += __shfl_xor(s, m);
      q += __shfl_xor(q, m);
    }
    float mean = s * (1.0f / 256.0f);
    float var = q * (1.0f / 256.0f) - mean * mean;
    float rstd = rsqrtf(var + 1e-5f);
    int row = (r & 3) + ((r >> 2) << 3) + (half << 2);  // C/D layout, 32x32
    int grow = m_base + row;
    if (grow < NN) {
#pragma unroll
      for (int t = 0; t < 8; ++t) {
        float v = (acc[t][r] - mean) * rstd * gc[t] + bc[t];
        out[(size_t)grow * 256 + t * 32 + l31] = fmaxf(v, 0.0f);
      }
    }
  }
}

extern "C" void kernel_launch(void* const* d_in, const int* in_sizes, int n_in,
                              void* d_out, int out_size, void* d_ws, size_t ws_size,
                              hipStream_t stream) {
  const float* x      = (const float*)d_in[0];
  const int*   src    = (const int*)d_in[1];
  const int*   dst    = (const int*)d_in[2];
  const float* bases  = (const float*)d_in[3];
  const float* w_comp = (const float*)d_in[4];
  const float* loop_w = (const float*)d_in[5];
  const float* h_bias = (const float*)d_in[6];
  const float* gamma  = (const float*)d_in[7];
  const float* beta   = (const float*)d_in[8];
  float* out = (float*)d_out;

  char* ws = (char*)d_ws;
  unsigned short* Cp    = (unsigned short*)ws;                // 102,400,000 B
  unsigned short* Xbf   = (unsigned short*)(ws + 102400000);  //  51,200,000 B
  unsigned short* Bfrag = (unsigned short*)(ws + 153600000);  //     393,216 B
  int* cnt     = (int*)(ws + 153993216);                      //     400,000 B
  int* edgebuf = (int*)(ws + 154393216);                      //  12,800,000 B
  // total 167,193,216 B

  hipMemsetAsync(cnt, 0, 400000, stream);

  prep<<<16393, 256, 0, stream>>>(x, bases, loop_w, src, dst, Xbf, Bfrag, cnt, edgebuf);
  agg_edges<<<12500, 256, 0, stream>>>(edgebuf, cnt, w_comp, Xbf, Cp);
  gemm_ln<<<(NN + BM - 1) / BM, 256, 0, stream>>>(Cp, Xbf, Bfrag, h_bias, gamma, beta, out);
}